// Round 18
// baseline (1583.411 us; speedup 1.0000x reference)
//
#include <hip/hip_runtime.h>

#define BB 64
#define SS 2048
#define II 128
#define HH 256
#define OO 128

typedef _Float16 h2_t __attribute__((ext_vector_type(2)));

// Native 2-way f16 dot with f32 accumulate. v9/v10 counters showed ~910
// VALU-cyc/SIMD/step == the cvt+fma fallback count, i.e. the fdot2 builtin
// was NOT emitting v_dot2_f32_f16. Force it via inline asm.
__device__ __forceinline__ float fdot2(unsigned h, unsigned w, float acc) {
    float out;
    asm("v_dot2_f32_f16 %0, %1, %2, %3" : "=v"(out) : "v"(h), "v"(w), "v"(acc));
    return out;
}

// ---------------------------------------------------------------------------
// Prep: transpose W_ih -> [I][H], W_fc -> [H][O], combine biases, and write
// the SWIZZLED f16 weight buffer wsw (v9 layout, unchanged):
//   uint4 slot s = (w*16 + pair*8 + i)*64 + l  holds the chunk thread
//   (wave w, lane l) consumes as wA[i] (pair=0) / wB[i] (pair=1):
//   row j = w*32 + (l&15)*2 + pair, dwords (l>>4)*32 + i*4 .. +3.
// ---------------------------------------------------------------------------
__global__ void prep_kernel(const float* __restrict__ W_ih, const float* __restrict__ b_ih,
                            const float* __restrict__ b_hh, const float* __restrict__ W_fc,
                            float* __restrict__ wihT, float* __restrict__ wfcT,
                            float* __restrict__ biasc, unsigned* __restrict__ wsw,
                            const float* __restrict__ W_hh) {
    int idx = blockIdx.x * 256 + threadIdx.x;      // grid 128*256 = 32768
    if (idx < HH * II) {            // W_ih [H][I] -> wihT [I][H]
        int j = idx / II, k = idx % II;
        wihT[k * HH + j] = W_ih[idx];
    }
    if (idx < OO * HH) {            // W_fc [O][H] -> wfcT [H][O]
        int j = idx / HH, k = idx % HH;
        wfcT[k * OO + j] = W_fc[idx];
    }
    if (idx < HH * (HH / 2)) {      // swizzled scan weights (32768 dwords)
        int d   = idx & 3;
        int s   = idx >> 2;
        int l   = s & 63;
        int rem = s >> 6;
        int i    = rem & 7;
        int pair = (rem >> 3) & 1;
        int w    = rem >> 4;
        int j    = w * 32 + (l & 15) * 2 + pair;
        int word = (l >> 4) * 32 + i * 4 + d;      // dword index within row j
        union { h2_t h; unsigned u; } pk;
        pk.h.x = (_Float16)W_hh[j * HH + 2 * word];
        pk.h.y = (_Float16)W_hh[j * HH + 2 * word + 1];
        wsw[idx] = pk.u;
    }
    if (idx < HH) biasc[idx] = b_ih[idx] + b_hh[idx];
}

// ---------------------------------------------------------------------------
// Generic row-major GEMM: C[r][j] = sum_k A[r][k] * Wt[k][j] + bias[j]
// 256 threads, 8x8 micro-tile per thread. (unchanged — scan dominates)
// ---------------------------------------------------------------------------
template<int KD, int JD, int RT>
__global__ __launch_bounds__(256, 2)
void gemm_rk(const float* __restrict__ A, const float* __restrict__ Wt,
             const float* __restrict__ bias, float* __restrict__ C) {
    constexpr int KT = 64;
    constexpr int TJ = JD / 8;
    constexpr int TR = RT / 8;
    static_assert(TJ * TR == 256, "bad tiling");

    __shared__ __align__(16) float a_lds[RT][KT];
    __shared__ __align__(16) float w_lds[KT][JD];

    const int tid = threadIdx.x;
    const int tj = tid % TJ;
    const int tr = tid / TJ;
    const long r0 = (long)blockIdx.x * RT;

    float acc[8][8];
#pragma unroll
    for (int r = 0; r < 8; ++r)
#pragma unroll
        for (int j = 0; j < 8; ++j) acc[r][j] = 0.0f;

    for (int kt = 0; kt < KD; kt += KT) {
        {
            constexpr int NF4 = RT * KT / 4;
#pragma unroll
            for (int f = 0; f < NF4 / 256; ++f) {
                int fl = f * 256 + tid;
                int rr = fl / (KT / 4), kk4 = fl % (KT / 4);
                *(float4*)&a_lds[rr][kk4 * 4] =
                    *(const float4*)&A[(r0 + rr) * KD + kt + kk4 * 4];
            }
        }
        {
            constexpr int NF4 = KT * JD / 4;
#pragma unroll
            for (int f = 0; f < NF4 / 256; ++f) {
                int fl = f * 256 + tid;
                int kk = fl / (JD / 4), jj4 = fl % (JD / 4);
                *(float4*)&w_lds[kk][jj4 * 4] =
                    *(const float4*)&Wt[(long)(kt + kk) * JD + jj4 * 4];
            }
        }
        __syncthreads();

#pragma unroll 4
        for (int k4 = 0; k4 < KT; k4 += 4) {
            float4 xv[8];
#pragma unroll
            for (int r = 0; r < 8; ++r)
                xv[r] = *(const float4*)&a_lds[tr * 8 + r][k4];
#pragma unroll
            for (int i = 0; i < 4; ++i) {
                float4 wa = *(const float4*)&w_lds[k4 + i][tj * 8];
                float4 wb = *(const float4*)&w_lds[k4 + i][tj * 8 + 4];
#pragma unroll
                for (int r = 0; r < 8; ++r) {
                    float xs = (i == 0) ? xv[r].x : (i == 1) ? xv[r].y
                             : (i == 2) ? xv[r].z : xv[r].w;
                    acc[r][0] = fmaf(xs, wa.x, acc[r][0]);
                    acc[r][1] = fmaf(xs, wa.y, acc[r][1]);
                    acc[r][2] = fmaf(xs, wa.z, acc[r][2]);
                    acc[r][3] = fmaf(xs, wa.w, acc[r][3]);
                    acc[r][4] = fmaf(xs, wb.x, acc[r][4]);
                    acc[r][5] = fmaf(xs, wb.y, acc[r][5]);
                    acc[r][6] = fmaf(xs, wb.z, acc[r][6]);
                    acc[r][7] = fmaf(xs, wb.w, acc[r][7]);
                }
            }
        }
        __syncthreads();
    }

    float4 b0 = *(const float4*)&bias[tj * 8];
    float4 b1 = *(const float4*)&bias[tj * 8 + 4];
#pragma unroll
    for (int r = 0; r < 8; ++r) {
        long row = r0 + tr * 8 + r;
        float4 o0, o1;
        o0.x = acc[r][0] + b0.x; o0.y = acc[r][1] + b0.y;
        o0.z = acc[r][2] + b0.z; o0.w = acc[r][3] + b0.w;
        o1.x = acc[r][4] + b1.x; o1.y = acc[r][5] + b1.y;
        o1.z = acc[r][6] + b1.z; o1.w = acc[r][7] + b1.w;
        *(float4*)&C[row * JD + tj * 8]     = o0;
        *(float4*)&C[row * JD + tj * 8 + 4] = o1;
    }
}

// ---------------------------------------------------------------------------
// Sequential scan v11 = v9 (best measured: 1256us) + native v_dot2_f32_f16
// + pointer-split weight bases (imm offsets <= 3072B, no 64b addr arith).
// 64 blocks x 512 threads (8 waves), weights stream from L2, one barrier
// per step, double-buffered f16 h in LDS, butterfly shfl_xor(16,32) reduce.
// ---------------------------------------------------------------------------
__global__ __attribute__((amdgpu_waves_per_eu(2, 2))) __launch_bounds__(512)
void rnn_scan(const unsigned* __restrict__ wsw, float* __restrict__ hid) {
    const int b   = blockIdx.x;
    const int tid = threadIdx.x;
    const int w   = tid >> 6;
    const int l   = tid & 63;
    const int sl  = l & 15;
    const int q   = l >> 4;

    const int j0 = w * 32 + sl * 2;      // two outputs j0, j0+1

    __shared__ __align__(16) unsigned h16[2][4 * 36];

    // weight stream bases, split so every load uses a small imm offset
    const uint4* __restrict__ wpA0 = (const uint4*)wsw + ((size_t)w << 10) + l;
    const uint4* __restrict__ wpA1 = wpA0 + 256;   // wA[4..7]
    const uint4* __restrict__ wpB0 = wpA0 + 512;   // wB[0..3]
    const uint4* __restrict__ wpB1 = wpA0 + 768;   // wB[4..7]

    for (int i = tid; i < 2 * 4 * 36; i += 512) ((unsigned*)h16)[i] = 0u;

    float* __restrict__ base = hid + (size_t)b * SS * HH;
    float2 xp0 = *(const float2*)&base[j0];
    float2 xp1 = *(const float2*)&base[HH + j0];
    __syncthreads();

#pragma unroll 1
    for (int t = 0; t < SS; ++t) {
        // stream this step's weights from L2 (coalesced 1KB/instr)
        uint4 wA[8], wB[8];
#pragma unroll
        for (int i = 0; i < 4; ++i) {
            wA[i]     = wpA0[i * 64];
            wA[4 + i] = wpA1[i * 64];
            wB[i]     = wpB0[i * 64];
            wB[4 + i] = wpB1[i * 64];
        }

        // prefetch xproj for t+2 (read precedes the overwrite at t)
        float2 xp2 = make_float2(0.f, 0.f);
        if (t + 2 < SS) xp2 = *(const float2*)&base[(size_t)(t + 2) * HH + j0];

        const uint4* hb = (const uint4*)&h16[t & 1][q * 36];
        float aA0 = 0.f, aA1 = 0.f, aB0 = 0.f, aB1 = 0.f;
#pragma unroll
        for (int i = 0; i < 8; ++i) {
            uint4 hv = hb[i];
            aA0 = fdot2(hv.x, wA[i].x, aA0);
            aA1 = fdot2(hv.y, wA[i].y, aA1);
            aA0 = fdot2(hv.z, wA[i].z, aA0);
            aA1 = fdot2(hv.w, wA[i].w, aA1);
            aB0 = fdot2(hv.x, wB[i].x, aB0);
            aB1 = fdot2(hv.y, wB[i].y, aB1);
            aB0 = fdot2(hv.z, wB[i].z, aB0);
            aB1 = fdot2(hv.w, wB[i].w, aB1);
        }
        float sA = aA0 + aA1;
        float sB = aB0 + aB1;
        // butterfly over the 4 k-quarters (lanes sl, sl+16, sl+32, sl+48)
        sA += __shfl_xor(sA, 16, 64);
        sA += __shfl_xor(sA, 32, 64);
        sB += __shfl_xor(sB, 16, 64);
        sB += __shfl_xor(sB, 32, 64);

        float s0 = xp0.x + sA;
        float s1 = xp0.y + sB;
        // tanh(s) = 1 - 2/(e^{2s}+1); overflow-safe without clamps
        float e0  = __expf(2.0f * s0);
        float e1  = __expf(2.0f * s1);
        float hn0 = 1.0f - __fdividef(2.0f, e0 + 1.0f);
        float hn1 = 1.0f - __fdividef(2.0f, e1 + 1.0f);

        if (q == 0) {
            union { h2_t h; unsigned u; } pk;
            pk.h.x = (_Float16)hn0;
            pk.h.y = (_Float16)hn1;
            const int W = j0 >> 1;
            h16[(t & 1) ^ 1][(W >> 5) * 36 + (W & 31)] = pk.u;
            *(float2*)&base[(size_t)t * HH + j0] = make_float2(hn0, hn1);
        }
        __syncthreads();
        xp0 = xp1;
        xp1 = xp2;
    }
}

// ---------------------------------------------------------------------------
extern "C" void kernel_launch(void* const* d_in, const int* in_sizes, int n_in,
                              void* d_out, int out_size, void* d_ws, size_t ws_size,
                              hipStream_t stream) {
    const float* x    = (const float*)d_in[0];
    const float* W_ih = (const float*)d_in[1];
    const float* W_hh = (const float*)d_in[2];
    const float* b_ih = (const float*)d_in[3];
    const float* b_hh = (const float*)d_in[4];
    const float* W_fc = (const float*)d_in[5];
    const float* b_fc = (const float*)d_in[6];

    float* out_fc  = (float*)d_out;                          // [B][S][O]
    float* hidden  = (float*)d_out + (size_t)BB * SS * OO;   // [B][S][H]

    float*    wihT  = (float*)d_ws;                  // [I][H]  32768 f
    float*    wfcT  = wihT + II * HH;                // [H][O]  32768 f
    float*    biasc = wfcT + HH * OO;                // [H]       256 f
    unsigned* wsw   = (unsigned*)(biasc + HH);       // swizzled [32768] u32

    const long NR = (long)BB * SS;                   // 131072 rows

    prep_kernel<<<128, 256, 0, stream>>>(W_ih, b_ih, b_hh, W_fc,
                                         wihT, wfcT, biasc, wsw, W_hh);
    gemm_rk<II, HH, 64><<<NR / 64, 256, 0, stream>>>(x, wihT, biasc, hidden);
    rnn_scan<<<BB, 512, 0, stream>>>(wsw, hidden);
    gemm_rk<HH, OO, 128><<<NR / 128, 256, 0, stream>>>(hidden, wfcT, b_fc, out_fc);
}